// Round 15
// baseline (478.769 us; speedup 1.0000x reference)
//
#include <hip/hip_runtime.h>
#include <math.h>

#define N_TOK 4096
#define DM 1024
#define DFF 4096
#define DN 128
#define NH 8
#define HD 16
#define KSEL 32
#define KCAND 48
#define KMAX 64

typedef __attribute__((ext_vector_type(4))) float floatx4;
typedef __attribute__((ext_vector_type(8))) short short8;
typedef __attribute__((ext_vector_type(8))) unsigned short ushort8v;
typedef __attribute__((ext_vector_type(4))) unsigned short ushort4v;

__device__ __forceinline__ float gelu_f(float x) {
  return 0.5f * x * (1.0f + erff(x * 0.70710678118654752440f));
}
__device__ __forceinline__ float bf2f(unsigned short u) {
  union { unsigned int i; float f; } v; v.i = ((unsigned int)u) << 16; return v.f;
}
__device__ __forceinline__ unsigned short f2bf(float f) {
  unsigned int x = __float_as_uint(f);
  unsigned int r = (x + 0x7fffu + ((x >> 16) & 1u)) >> 16;
  return (unsigned short)r;
}
// triple-bf16 split: v = hi + mid + lo to ~24 significant bits
__device__ __forceinline__ void split3(float v, unsigned short& h, unsigned short& m,
                                       unsigned short& lo) {
  h = f2bf(v);
  float r1 = v - bf2f(h);
  m = f2bf(r1);
  float r2 = r1 - bf2f(m);
  lo = f2bf(r2);
}

// ---------------- prep: LayerNorm + all weight conversions + qkv table, ONE launch ----------------
// blocks [0,4096): ln3 | [4096,16384): cvt {rw2,pats,dirs} | [16384,16400): opw
// [16400,16408): w1 | [16408,17432): rw1-split3 | [17432,18456): qkvtab (4 neurons/block)
__global__ __launch_bounds__(256) void prep_kernel(
    const float* __restrict__ x, const float* __restrict__ g, const float* __restrict__ bb_,
    unsigned short* __restrict__ xh, unsigned short* __restrict__ xm,
    unsigned short* __restrict__ xl,
    const float* __restrict__ rw2, unsigned short* __restrict__ w2b,
    const float* __restrict__ pats, unsigned short* __restrict__ patsb,
    const float* __restrict__ dirs, unsigned short* __restrict__ dirsb,
    const float* __restrict__ opw, unsigned short* __restrict__ opwb,
    const float* __restrict__ w1, unsigned short* __restrict__ w1b,
    const float* __restrict__ rw1, unsigned short* __restrict__ w1h,
    unsigned short* __restrict__ w1m, unsigned short* __restrict__ w1l,
    const float* __restrict__ nv, const float* __restrict__ ipw,
    const float* __restrict__ ipb, unsigned short* __restrict__ tab) {
  int b = blockIdx.x, t = threadIdx.x;
  if (b < 4096) {
    int n = b;
    const float* row = x + (size_t)n * DM;
    float s = 0.f, sq = 0.f;
    for (int i = t; i < DM; i += 256) { float v = row[i]; s += v; sq += v * v; }
    for (int off = 32; off; off >>= 1) { s += __shfl_down(s, off); sq += __shfl_down(sq, off); }
    __shared__ float ss[4], ssq[4];
    __shared__ float s_mu, s_rs;
    int wid = t >> 6;
    if ((t & 63) == 0) { ss[wid] = s; ssq[wid] = sq; }
    __syncthreads();
    if (t == 0) {
      float S = ss[0] + ss[1] + ss[2] + ss[3];
      float Q = ssq[0] + ssq[1] + ssq[2] + ssq[3];
      float mu = S * (1.f / DM);
      float var = Q * (1.f / DM) - mu * mu;
      s_mu = mu; s_rs = rsqrtf(var + 1e-5f);
    }
    __syncthreads();
    float mu = s_mu, rs = s_rs;
    size_t base = (size_t)n * DM;
    for (int i = t; i < DM; i += 256) {
      float v = (row[i] - mu) * rs * g[i] + bb_[i];
      unsigned short h, m, lo;
      split3(v, h, m, lo);
      xh[base + i] = h; xm[base + i] = m; xl[base + i] = lo;
    }
    return;
  }
  int bp = b - 4096;
  if (bp < 12288) {
    const float* src; unsigned short* dst; int local;
    if (bp < 4096) { src = rw2; dst = w2b; local = bp; }
    else if (bp < 8192) { src = pats; dst = patsb; local = bp - 4096; }
    else { src = dirs; dst = dirsb; local = bp - 8192; }
    int i = (local * 256 + t) * 4;
    float4 v = *(const float4*)(src + i);
    ushort4v o = {f2bf(v.x), f2bf(v.y), f2bf(v.z), f2bf(v.w)};
    *(ushort4v*)(dst + i) = o;
  } else if (bp < 12304) {
    int i = ((bp - 12288) * 256 + t) * 4;
    float4 v = *(const float4*)(opw + i);
    ushort4v o = {f2bf(v.x), f2bf(v.y), f2bf(v.z), f2bf(v.w)};
    *(ushort4v*)(opwb + i) = o;
  } else if (bp < 12312) {
    int i = ((bp - 12304) * 256 + t) * 4;
    float4 v = *(const float4*)(w1 + i);
    ushort4v o = {f2bf(v.x), f2bf(v.y), f2bf(v.z), f2bf(v.w)};
    *(ushort4v*)(w1b + i) = o;
  } else if (bp < 13336) {
    int i = ((bp - 12312) * 256 + t) * 4;
    float4 v = *(const float4*)(rw1 + i);
    unsigned short h0, m0, l0, h1, m1, l1, h2, m2, l2, h3, m3, l3;
    split3(v.x, h0, m0, l0);
    split3(v.y, h1, m1, l1);
    split3(v.z, h2, m2, l2);
    split3(v.w, h3, m3, l3);
    ushort4v hh = {h0, h1, h2, h3};
    ushort4v mm = {m0, m1, m2, m3};
    ushort4v ll = {l0, l1, l2, l3};
    *(ushort4v*)(w1h + i) = hh;
    *(ushort4v*)(w1m + i) = mm;
    *(ushort4v*)(w1l + i) = ll;
  } else {
    // qkvtab: 4 neurons per block, rows split t and t+256
    __shared__ float s_nv[4 * 128];
    int f0 = (bp - 13336) * 4;
    for (int i = t; i < 4 * 128; i += 256) s_nv[i] = nv[(size_t)f0 * 128 + i];
    __syncthreads();
    for (int row = t; row < 384; row += 256) {
      float bias = ipb[row];
      float acc[4];
#pragma unroll
      for (int ff = 0; ff < 4; ff++) acc[ff] = bias;
      const float* wr = ipw + (size_t)row * 128;
      for (int c = 0; c < 128; c++) {
        float wv = wr[c];
#pragma unroll
        for (int ff = 0; ff < 4; ff++) acc[ff] = fmaf(s_nv[ff * 128 + c], wv, acc[ff]);
      }
#pragma unroll
      for (int ff = 0; ff < 4; ff++) tab[(size_t)(f0 + ff) * 384 + row] = f2bf(acc[ff]);
    }
  }
}

// ---------------- gemm1: h = gelu(xn @ W1^T) via triple-bf16 MFMA ----------------
// 64x64 tile, 1024 blocks (4/CU, 16 waves/CU). Wave layout 2x2, acc[2][2].
__global__ __launch_bounds__(256) void gemm1s(
    const unsigned short* __restrict__ Ah_, const unsigned short* __restrict__ Am_,
    const unsigned short* __restrict__ Al_, const unsigned short* __restrict__ Bh_,
    const unsigned short* __restrict__ Bm_, const unsigned short* __restrict__ Bl_,
    float* __restrict__ H, unsigned short* __restrict__ Hb) {
  __shared__ short Ahs[64 * 32], Ams[64 * 32], Als[64 * 32];
  __shared__ short Bhs[64 * 32], Bms[64 * 32], Bls[64 * 32];
  const int K = 1024;
  const int N = DM;
  int tid = threadIdx.x;
  int w = tid >> 6, l = tid & 63;
  int wr = w >> 1, wc = w & 1;
  size_t brow = (size_t)blockIdx.y * 64;
  size_t bcol = (size_t)blockIdx.x * 64;

  int r0 = w * 16 + (l >> 2);
  int g0 = (l & 3) ^ ((r0 >> 1) & 3);
  size_t oA = (brow + r0) * (size_t)K + g0 * 8;
  size_t oB = (bcol + r0) * (size_t)K + g0 * 8;
  const short* gAh = (const short*)Ah_ + oA;
  const short* gAm = (const short*)Am_ + oA;
  const short* gAl = (const short*)Al_ + oA;
  const short* gBh = (const short*)Bh_ + oB;
  const short* gBm = (const short*)Bm_ + oB;
  const short* gBl = (const short*)Bl_ + oB;
  short* lAh = &Ahs[w * 512]; short* lAm = &Ams[w * 512]; short* lAl = &Als[w * 512];
  short* lBh = &Bhs[w * 512]; short* lBm = &Bms[w * 512]; short* lBl = &Bls[w * 512];

  const short8 *pah[2], *pam[2], *pal[2], *pbh[2], *pbm[2], *pbl[2];
#pragma unroll
  for (int i = 0; i < 2; i++) {
    int m = wr * 32 + i * 16 + (l & 15);
    int slot = m * 4 + ((l >> 4) ^ ((m >> 1) & 3));
    pah[i] = (const short8*)&Ahs[slot * 8];
    pam[i] = (const short8*)&Ams[slot * 8];
    pal[i] = (const short8*)&Als[slot * 8];
    int nn = wc * 32 + i * 16 + (l & 15);
    int slotb = nn * 4 + ((l >> 4) ^ ((nn >> 1) & 3));
    pbh[i] = (const short8*)&Bhs[slotb * 8];
    pbm[i] = (const short8*)&Bms[slotb * 8];
    pbl[i] = (const short8*)&Bls[slotb * 8];
  }

  floatx4 acc[2][2];
#pragma unroll
  for (int i = 0; i < 2; i++)
#pragma unroll
    for (int j = 0; j < 2; j++) acc[i][j] = (floatx4){0.f, 0.f, 0.f, 0.f};

#define GLD(GP, LB) \
  __builtin_amdgcn_global_load_lds((const __attribute__((address_space(1))) unsigned int*)(GP), \
                                   (__attribute__((address_space(3))) unsigned int*)(LB), 16, 0, 0)

  for (int k0 = 0; k0 < K; k0 += 32) {
    __syncthreads();
    GLD(gAh + k0, lAh); GLD(gAm + k0, lAm); GLD(gAl + k0, lAl);
    GLD(gBh + k0, lBh); GLD(gBm + k0, lBm); GLD(gBl + k0, lBl);
    __syncthreads();
    short8 ah[2], am[2], al[2], bh[2], bm[2], bl[2];
#pragma unroll
    for (int i = 0; i < 2; i++) {
      ah[i] = *pah[i]; am[i] = *pam[i]; al[i] = *pal[i];
      bh[i] = *pbh[i]; bm[i] = *pbm[i]; bl[i] = *pbl[i];
    }
    // 6 split-product passes (hh, mh, hm, lh, hl, mm)
#pragma unroll
    for (int i = 0; i < 2; i++)
#pragma unroll
      for (int j = 0; j < 2; j++)
        acc[i][j] = __builtin_amdgcn_mfma_f32_16x16x32_bf16(ah[i], bh[j], acc[i][j], 0, 0, 0);
#pragma unroll
    for (int i = 0; i < 2; i++)
#pragma unroll
      for (int j = 0; j < 2; j++)
        acc[i][j] = __builtin_amdgcn_mfma_f32_16x16x32_bf16(am[i], bh[j], acc[i][j], 0, 0, 0);
#pragma unroll
    for (int i = 0; i < 2; i++)
#pragma unroll
      for (int j = 0; j < 2; j++)
        acc[i][j] = __builtin_amdgcn_mfma_f32_16x16x32_bf16(ah[i], bm[j], acc[i][j], 0, 0, 0);
#pragma unroll
    for (int i = 0; i < 2; i++)
#pragma unroll
      for (int j = 0; j < 2; j++)
        acc[i][j] = __builtin_amdgcn_mfma_f32_16x16x32_bf16(al[i], bh[j], acc[i][j], 0, 0, 0);
#pragma unroll
    for (int i = 0; i < 2; i++)
#pragma unroll
      for (int j = 0; j < 2; j++)
        acc[i][j] = __builtin_amdgcn_mfma_f32_16x16x32_bf16(ah[i], bl[j], acc[i][j], 0, 0, 0);
#pragma unroll
    for (int i = 0; i < 2; i++)
#pragma unroll
      for (int j = 0; j < 2; j++)
        acc[i][j] = __builtin_amdgcn_mfma_f32_16x16x32_bf16(am[i], bm[j], acc[i][j], 0, 0, 0);
  }
#undef GLD

#pragma unroll
  for (int i = 0; i < 2; i++) {
#pragma unroll
    for (int j = 0; j < 2; j++) {
#pragma unroll
      for (int r = 0; r < 4; r++) {
        size_t row = brow + wr * 32 + i * 16 + (l >> 4) * 4 + r;
        size_t col = bcol + wc * 32 + j * 16 + (l & 15);
        float v = gelu_f(acc[i][j][r]);
        H[row * N + col] = v;
        Hb[row * N + col] = f2bf(v);
      }
    }
  }
}

// ---------------- bf16 MFMA GEMM: scores_approx(bf16) = hb @ w2b^T ----------------
__global__ __launch_bounds__(256) void gemm_bf(const unsigned short* __restrict__ Ah,
    const unsigned short* __restrict__ Bh, unsigned short* __restrict__ C) {
  __shared__ short Asd[128 * 32];
  __shared__ short Bsd[128 * 32];
  const int K = 1024;
  int tid = threadIdx.x;
  int w = tid >> 6, l = tid & 63;
  size_t brow = (size_t)blockIdx.y * 128;
  size_t bcol = (size_t)blockIdx.x * 128;
  const short* Ab = (const short*)Ah + brow * K;
  const short* Bb = (const short*)Bh + bcol * K;

  int r0 = w * 32 + (l >> 2);
  int g0 = (l & 3) ^ ((r0 >> 1) & 3);
  const short* Ag0 = Ab + (size_t)r0 * K + g0 * 8;
  const short* Ag1 = Ab + (size_t)(r0 + 16) * K + g0 * 8;
  const short* Bg0 = Bb + (size_t)r0 * K + g0 * 8;
  const short* Bg1 = Bb + (size_t)(r0 + 16) * K + g0 * 8;
  short* ALds0 = &Asd[w * 1024];
  short* ALds1 = &Asd[w * 1024 + 512];
  short* BLds0 = &Bsd[w * 1024];
  short* BLds1 = &Bsd[w * 1024 + 512];

  const short8* aptr[4];
  const short8* bptr[4];
#pragma unroll
  for (int i = 0; i < 4; i++) {
    int m = (w >> 1) * 64 + i * 16 + (l & 15);
    int slot = m * 4 + ((l >> 4) ^ ((m >> 1) & 3));
    aptr[i] = (const short8*)&Asd[slot * 8];
    int n = (w & 1) * 64 + i * 16 + (l & 15);
    int slotb = n * 4 + ((l >> 4) ^ ((n >> 1) & 3));
    bptr[i] = (const short8*)&Bsd[slotb * 8];
  }

  floatx4 acc[4][4];
#pragma unroll
  for (int i = 0; i < 4; i++)
#pragma unroll
    for (int j = 0; j < 4; j++) acc[i][j] = (floatx4){0.f, 0.f, 0.f, 0.f};

  for (int k0 = 0; k0 < K; k0 += 32) {
    __syncthreads();
    __builtin_amdgcn_global_load_lds((const __attribute__((address_space(1))) unsigned int*)(Ag0 + k0),
                                     (__attribute__((address_space(3))) unsigned int*)ALds0, 16, 0, 0);
    __builtin_amdgcn_global_load_lds((const __attribute__((address_space(1))) unsigned int*)(Ag1 + k0),
                                     (__attribute__((address_space(3))) unsigned int*)ALds1, 16, 0, 0);
    __builtin_amdgcn_global_load_lds((const __attribute__((address_space(1))) unsigned int*)(Bg0 + k0),
                                     (__attribute__((address_space(3))) unsigned int*)BLds0, 16, 0, 0);
    __builtin_amdgcn_global_load_lds((const __attribute__((address_space(1))) unsigned int*)(Bg1 + k0),
                                     (__attribute__((address_space(3))) unsigned int*)BLds1, 16, 0, 0);
    __syncthreads();
    short8 a[4], b[4];
#pragma unroll
    for (int i = 0; i < 4; i++) a[i] = *aptr[i];
#pragma unroll
    for (int j = 0; j < 4; j++) b[j] = *bptr[j];
#pragma unroll
    for (int i = 0; i < 4; i++)
#pragma unroll
      for (int j = 0; j < 4; j++)
        acc[i][j] = __builtin_amdgcn_mfma_f32_16x16x32_bf16(a[i], b[j], acc[i][j], 0, 0, 0);
  }

#pragma unroll
  for (int i = 0; i < 4; i++) {
#pragma unroll
    for (int j = 0; j < 4; j++) {
#pragma unroll
      for (int r = 0; r < 4; r++) {
        size_t row = brow + (w >> 1) * 64 + i * 16 + (l >> 4) * 4 + r;
        size_t col = bcol + (w & 1) * 64 + j * 16 + (l & 15);
        C[row * DFF + col] = f2bf(acc[i][j][r]);
      }
    }
  }
}

// ---------------- top-candidates per row: wave-per-token radix select ----------------
__global__ __launch_bounds__(256) void topk2_kernel(const unsigned short* __restrict__ scores,
    int* __restrict__ cand, int* __restrict__ cnt) {
  int wv = threadIdx.x >> 6, l = threadIdx.x & 63;
  int n = blockIdx.x * 4 + wv;
  const ushort8v* row = (const ushort8v*)(scores + (size_t)n * DFF);
  unsigned short key[64];
#pragma unroll
  for (int i = 0; i < 8; i++) {
    ushort8v v = row[l * 8 + i];
#pragma unroll
    for (int e = 0; e < 8; e++) {
      unsigned short u = v[e];
      key[i * 8 + e] = (u & 0x8000u) ? (unsigned short)(~u)
                                     : (unsigned short)(u | 0x8000u);
    }
  }
  unsigned int prefix = 0;
#pragma unroll
  for (int bit = 15; bit >= 0; bit--) {
    unsigned int probe = prefix | (1u << bit);
    int c = 0;
#pragma unroll
    for (int i = 0; i < 64; i++) c += (key[i] >= probe) ? 1 : 0;
#pragma unroll
    for (int s = 1; s < 64; s <<= 1) c += __shfl_xor(c, s);
    if (c >= KCAND) prefix = probe;
  }
  unsigned short thr = (unsigned short)prefix;
  unsigned long long ltmask = (1ull << l) - 1ull;
  int base = 0;
  int* outp = cand + (size_t)n * KMAX;
#pragma unroll
  for (int i = 0; i < 64; i++) {
    bool p = key[i] >= thr;
    unsigned long long m = __ballot(p);
    if (p) {
      int pos = base + __popcll(m & ltmask);
      if (pos < KMAX) outp[pos] = l * 64 + i;
    }
    base += __popcll(m);
  }
  if (l == 0) cnt[n] = base < KMAX ? base : KMAX;
}

// ---------------- fp32 rescore of candidates -> exact top-32 set ----------------
__global__ __launch_bounds__(256) void rescore_kernel(const float* __restrict__ h,
    const float* __restrict__ w2f, const int* __restrict__ cand,
    const int* __restrict__ cnt, int* __restrict__ idx32) {
  __shared__ float sh[DM];
  __shared__ float sc[KMAX];
  __shared__ int sidx[KMAX];
  __shared__ int s_cnt;
  int n = blockIdx.x, tid = threadIdx.x;
  *(float4*)&sh[tid * 4] = *(const float4*)(h + (size_t)n * DM + tid * 4);
  if (tid == 0) s_cnt = cnt[n];
  if (tid < KMAX) { sidx[tid] = cand[(size_t)n * KMAX + tid]; sc[tid] = -INFINITY; }
  __syncthreads();
  int cntv = s_cnt;
  int w = tid >> 6, lane = tid & 63;
  for (int c = w; c < cntv; c += 4) {
    const float4* row = (const float4*)(w2f + (size_t)sidx[c] * DM);
    const float4* hp = (const float4*)sh;
    float s = 0.f;
#pragma unroll
    for (int t = 0; t < 4; t++) {
      float4 wv = row[t * 64 + lane];
      float4 hv = hp[t * 64 + lane];
      s = fmaf(wv.x, hv.x, s); s = fmaf(wv.y, hv.y, s);
      s = fmaf(wv.z, hv.z, s); s = fmaf(wv.w, hv.w, s);
    }
    for (int off = 32; off; off >>= 1) s += __shfl_xor(s, off);
    if (lane == 0) sc[c] = s;
  }
  __syncthreads();
  if (tid < cntv) {
    float st = sc[tid]; int it = sidx[tid];
    int rank = 0;
    for (int j = 0; j < KMAX; j++) {
      float sj = sc[j];
      rank += (sj > st) || (sj == st && sidx[j] < it);
    }
    if (rank < KSEL) idx32[(size_t)n * KSEL + rank] = it;
  }
}

// ---------------- tail v9b: 2 tokens/block (512 thr); MFMA attention per 4-wave half ----------------
#define KS 132
#define AOS 132
__global__ __launch_bounds__(512) void tail9_kernel(
    const float* __restrict__ xf, const unsigned short* __restrict__ pats_b,
    const unsigned short* __restrict__ dirs_b, const unsigned short* __restrict__ qtab_b,
    const int* __restrict__ idxs,
    const unsigned short* __restrict__ opwb, const float* __restrict__ opb,
    const unsigned short* __restrict__ w1b, const float* __restrict__ b1,
    const float* __restrict__ w2, const float* __restrict__ b2,
    float* __restrict__ out) {
  __shared__ unsigned short s_q[2][32 * KS];
  __shared__ unsigned short s_k[2][32 * KS];
  __shared__ unsigned short s_v[2][32 * KS];
  __shared__ float s_base[2][32];
  __shared__ float s_coef[2][32];
  __shared__ int s_idx[2][32];

  int tid512 = threadIdx.x;
  int tk = tid512 >> 8;                       // token half 0/1
  int tid = tid512 & 255;                     // 0..255 within half
  int n = blockIdx.x * 2 + tk;
  int w = tid >> 6, l = tid & 63;
  int g = l >> 4, lc = l & 15;
  unsigned short* s_ao = s_k[tk];             // aliases within this token's buffers
  unsigned short* s_at = s_v[tk];

  if (tid < 32) s_idx[tk][tid] = idxs[(size_t)n * 32 + tid];
  __syncthreads();   // s_idx ready (both tokens)

  // stage Q, K, V row-major (conflict-free 16B stores)
#pragma unroll
  for (int p = 0; p < 2; p++) {
    int i = p * 256 + tid;
    int j = i >> 4, cc = i & 15;
    const unsigned short* src = qtab_b + (size_t)s_idx[tk][j] * 384 + cc * 8;
    ushort8v qv = *(const ushort8v*)(src);
    ushort8v kv = *(const ushort8v*)(src + 128);
    ushort8v vv = *(const ushort8v*)(src + 256);
    *(ushort8v*)&s_q[tk][j * KS + cc * 8] = qv;
    *(ushort8v*)&s_k[tk][j * KS + cc * 8] = kv;
    *(ushort8v*)&s_v[tk][j * KS + cc * 8] = vv;
  }

  // base[j] = gelu(x . pats[idx[j]]) : 32 groups x 8 lanes; x from global (L1)
  {
    int j = tid >> 3, gq = tid & 7;
    const ushort8v* pr = (const ushort8v*)(pats_b + (size_t)s_idx[tk][j] * DM);
    const float4* xr = (const float4*)(xf + (size_t)n * DM);
    float s = 0.f;
#pragma unroll 4
    for (int it = 0; it < 16; it++) {
      int ch = it * 8 + gq;
      ushort8v pv = pr[ch];
      float4 xv0 = xr[ch * 2];
      float4 xv1 = xr[ch * 2 + 1];
      s = fmaf(bf2f(pv[0]), xv0.x, s); s = fmaf(bf2f(pv[1]), xv0.y, s);
      s = fmaf(bf2f(pv[2]), xv0.z, s); s = fmaf(bf2f(pv[3]), xv0.w, s);
      s = fmaf(bf2f(pv[4]), xv1.x, s); s = fmaf(bf2f(pv[5]), xv1.y, s);
      s = fmaf(bf2f(pv[6]), xv1.z, s); s = fmaf(bf2f(pv[7]), xv1.w, s);
    }
    s += __shfl_xor(s, 1);
    s += __shfl_xor(s, 2);
    s += __shfl_xor(s, 4);
    if (gq == 0) s_base[tk][j] = gelu_f(s);
  }
  __syncthreads();   // Q/K/V staged

  // ---- QK (swapped, MFMA) + softmax + P^T repack ----
  short8 pB[2][2];
  {
    short8 zero8 = {0, 0, 0, 0, 0, 0, 0, 0};
    int srcA = (((2 * g) & 3) << 4) | lc;
    int srcB = (((2 * g + 1) & 3) << 4) | lc;
    bool hiSel = (g >= 2);
#pragma unroll
    for (int hh = 0; hh < 2; hh++) {
      int h = w * 2 + hh;
      short8 qf[2], kf[2];
#pragma unroll
      for (int qt = 0; qt < 2; qt++) {
        short8 q = zero8;
        if (g < 2) q = *(const short8*)&s_q[tk][(qt * 16 + lc) * KS + h * 16 + g * 8];
        qf[qt] = q;
      }
#pragma unroll
      for (int kt = 0; kt < 2; kt++) {
        short8 k = zero8;
        if (g < 2) k = *(const short8*)&s_k[tk][(kt * 16 + lc) * KS + h * 16 + g * 8];
        kf[kt] = k;
      }
      floatx4 c[2][2];
#pragma unroll
      for (int kt = 0; kt < 2; kt++)
#pragma unroll
        for (int qt = 0; qt < 2; qt++)
          c[kt][qt] = __builtin_amdgcn_mfma_f32_16x16x32_bf16(kf[kt], qf[qt],
                                                              (floatx4){0.f, 0.f, 0.f, 0.f}, 0, 0, 0);
#pragma unroll
      for (int qt = 0; qt < 2; qt++) {
        float v0[4], v1[4];
#pragma unroll
        for (int r = 0; r < 4; r++) { v0[r] = c[0][qt][r] * 0.25f; v1[r] = c[1][qt][r] * 0.25f; }
        float m = v0[0];
#pragma unroll
        for (int r = 1; r < 4; r++) m = fmaxf(m, v0[r]);
#pragma unroll
        for (int r = 0; r < 4; r++) m = fmaxf(m, v1[r]);
        m = fmaxf(m, __shfl_xor(m, 16));
        m = fmaxf(m, __shfl_xor(m, 32));
        float sum = 0.f;
#pragma unroll
        for (int r = 0; r < 4; r++) { v0[r] = expf(v0[r] - m); sum += v0[r]; }
#pragma unroll
        for (int r = 0; r < 4; r++) { v1[r] = expf(v1[r] - m); sum += v1[r]; }
        sum += __shfl_xor(sum, 16);
        sum += __shfl_xor(sum, 32);
        float inv = 1.f / sum;
        unsigned int u00 = ((unsigned int)f2bf(v0[1] * inv) << 16) | f2bf(v0[0] * inv);
        unsigned int u01 = ((unsigned int)f2bf(v0[3] * inv) << 16) | f2bf(v0[2] * inv);
        unsigned int u10 = ((unsigned int)f2bf(v1[1] * inv) << 16) | f2bf(v1[0] * inv);
        unsigned int u11 = ((unsigned int)f2bf(v1[3] * inv) << 16) | f2bf(v1[2] * inv);
        unsigned int a00 = (unsigned int)__shfl((int)u00, srcA);
        unsigned int a01 = (unsigned int)__shfl((int)u01, srcA);
        unsigned int a10 = (unsigned int)__shfl((int)u10, srcA);
        unsigned int a11 = (unsigned int)__shfl((int)u11, srcA);
        unsigned int b00 = (unsigned int)__shfl((int)u00, srcB);
        unsigned int b01 = (unsigned int)__shfl((int)u01, srcB);
        unsigned int b10 = (unsigned int)__shfl((int)u10, srcB);
        unsigned int b11 = (unsigned int)__shfl((int)u11, srcB);
        union { unsigned int u[4]; short8 s; } pb;
        pb.u[0] = hiSel ? a10 : a00;
        pb.u[1] = hiSel ? a11 : a01;
        pb.u[2] = hiSel ? b10 : b00;
        pb.u[3] = hiSel ? b11 : b01;
        pB[hh][qt] = pb.s;
      }
    }
  }
  __syncthreads();   // QK reads done -> s_ao may overwrite

  // ---- PV (MFMA): V^T frag from row-major s_v ----
  {
#pragma unroll
    for (int hh = 0; hh < 2; hh++) {
      int h = w * 2 + hh;
      short8 vtf;
#pragma unroll
      for (int e = 0; e < 8; e++)
        vtf[e] = (short)s_v[tk][(g * 8 + e) * KS + h * 16 + lc];
#pragma unroll
      for (int qt = 0; qt < 2; qt++) {
        floatx4 o = __builtin_amdgcn_mfma_f32_16x16x32_bf16(vtf, pB[hh][qt],
                                                            (floatx4){0.f, 0.f, 0.f, 0.f}, 0, 0, 0);
        ushort4v ov = {f2bf(o[0]), f2bf(o[1]), f2bf(o[2]), f2bf(o[3])};
        *(ushort4v*)&s_ao[(qt * 16 + lc) * AOS + h * 16 + g * 4] = ov;
      }
    }
  }
  __syncthreads();   // PV reads done; s_ao complete -> s_at may overwrite s_v

  // out_proj MFMA: 4-wave split per token: rows (w&1)*16, col-block (w>>1)*64
  {
    floatx4 acc[4];
#pragma unroll
    for (int nt = 0; nt < 4; nt++) acc[nt] = (floatx4){0.f, 0.f, 0.f, 0.f};
    int rbase = (w & 1) * 16;
    int cblk = (w >> 1) * 4;
#pragma unroll
    for (int kst = 0; kst < 4; kst++) {
      short8 a = *(const short8*)&s_ao[(rbase + lc) * AOS + kst * 32 + g * 8];
#pragma unroll
      for (int nt = 0; nt < 4; nt++) {
        short8 b = *(const short8*)&opwb[(size_t)((cblk + nt) * 16 + lc) * 128 + kst * 32 + g * 8];
        acc[nt] = __builtin_amdgcn_mfma_f32_16x16x32_bf16(a, b, acc[nt], 0, 0, 0);
      }
    }
#pragma unroll
    for (int nt = 0; nt < 4; nt++) {
      int col = (cblk + nt) * 16 + lc;
      float bias = opb[col];
#pragma unroll
      for (int r = 0; r < 4; r++) {
        int row = rbase + g * 4 + r;
        s_at[row * AOS + col] = f2bf(acc[nt][r] + bias);
      }
    }
  }
  __syncthreads();

  // gate MFMA: waves 0-1 of each token half: rows w*16, all 64 cols
  if (w < 2) {
    floatx4 acc[4];
#pragma unroll
    for (int nt = 0; nt < 4; nt++) acc[nt] = (floatx4){0.f, 0.f, 0.f, 0.f};
#pragma unroll
    for (int kst = 0; kst < 4; kst++) {
      short8 a = *(const short8*)&s_at[(w * 16 + lc) * AOS + kst * 32 + g * 8];
#pragma unroll
      for (int nt = 0; nt < 4; nt++) {
        short8 b = *(const short8*)&w1b[(size_t)(nt * 16 + lc) * 128 + kst * 32 + g * 8];
        acc[nt] = __builtin_amdgcn_mfma_f32_16x16x32_bf16(a, b, acc[nt], 0, 0, 0);
      }
    }
    float p[4] = {0.f, 0.f, 0.f, 0.f};
#pragma unroll
    for (int nt = 0; nt < 4; nt++) {
      int col = nt * 16 + lc;
      float bb = b1[col], ww = w2[col];
#pragma unroll
      for (int r = 0; r < 4; r++)
        p[r] = fmaf(gelu_f(acc[nt][r] + bb), ww, p[r]);
    }
#pragma unroll
    for (int r = 0; r < 4; r++) {
      p[r] += __shfl_xor(p[r], 1);
      p[r] += __shfl_xor(p[r], 2);
      p[r] += __shfl_xor(p[r], 4);
      p[r] += __shfl_xor(p[r], 8);
    }
    if (lc == 0) {
      float b2v = b2[0];
#pragma unroll
      for (int r = 0; r < 4; r++) {
        int row = w * 16 + g * 4 + r;
        float sw = 1.f / (1.f + expf(-(p[r] + b2v)));
        s_coef[tk][row] = s_base[tk][row] * sw;
      }
    }
  }
  __syncthreads();

  // output: out[n][d] = sum_j coef[j] * dirs_b[idx[j]][d] (bf16 dirs)
  {
    int d0 = tid * 4;
    float4 a = {0.f, 0.f, 0.f, 0.f};
#pragma unroll 8
    for (int j = 0; j < 32; j++) {
      float c = s_coef[tk][j];
      ushort4v dv = *(const ushort4v*)&dirs_b[(size_t)s_idx[tk][j] * DM + d0];
      a.x = fmaf(c, bf2f(dv.x), a.x);
      a.y = fmaf(c, bf2f(dv.y), a.y);
      a.z = fmaf(c, bf2f(dv.z), a.z);
      a.w = fmaf(c, bf2f(dv.w), a.w);
    }
    *(float4*)&out[(size_t)n * 1024 + d0] = a;
  }
}

extern "C" void kernel_launch(void* const* d_in, const int* in_sizes, int n_in,
                              void* d_out, int out_size, void* d_ws, size_t ws_size,
                              hipStream_t stream) {
  const float* x    = (const float*)d_in[0];
  const float* pats = (const float*)d_in[1];
  const float* nv   = (const float*)d_in[2];
  const float* dirs = (const float*)d_in[3];
  const float* rw1  = (const float*)d_in[4];
  const float* rw2  = (const float*)d_in[5];
  const float* lng  = (const float*)d_in[6];
  const float* lnb  = (const float*)d_in[7];
  const float* ipw  = (const float*)d_in[8];
  const float* ipb  = (const float*)d_in[9];
  const float* opw  = (const float*)d_in[10];
  const float* opb  = (const float*)d_in[11];
  const float* w1   = (const float*)d_in[12];
  const float* b1   = (const float*)d_in[13];
  const float* w2   = (const float*)d_in[14];
  const float* b2   = (const float*)d_in[15];
  float* out = (float*)d_out;

  const size_t MB = 1u << 20;
  char* ws = (char*)d_ws;
  unsigned short* xnh  = (unsigned short*)(ws + 0);        // 8 MB (split xn hi)
  unsigned short* xnm  = (unsigned short*)(ws + 8 * MB);   // 8 MB (split xn mid)
  float* h             = (float*)(ws + 16 * MB);           // 16 MB
  unsigned short* sb   = (unsigned short*)(ws + 32 * MB);  // 32 MB (bf16 scores)
  // transient buffers inside sb region: consumed by gemm1s BEFORE gemm_bf writes sb
  unsigned short* w1h  = (unsigned short*)(ws + 32 * MB);  // 2 MB
  unsigned short* w1m  = (unsigned short*)(ws + 34 * MB);  // 2 MB
  unsigned short* w1l  = (unsigned short*)(ws + 36 * MB);  // 2 MB
  unsigned short* xnl  = (unsigned short*)(ws + 38 * MB);  // 8 MB (split xn lo)
  unsigned short* qtab = (unsigned short*)(ws + 64 * MB);  // 3 MB
  unsigned short* hb   = (unsigned short*)(ws + 67 * MB);  // 8 MB
  unsigned short* w2b  = (unsigned short*)(ws + 75 * MB);  // 8 MB
  unsigned short* patsb= (unsigned short*)(ws + 83 * MB);  // 8 MB
  unsigned short* dirsb= (unsigned short*)(ws + 91 * MB);  // 8 MB
  unsigned short* opwb = (unsigned short*)(ws + 99 * MB);  // 32 KB
  unsigned short* w1b  = (unsigned short*)(ws + 99 * MB + 64 * 1024);  // 16 KB
  int* idx32           = (int*)(ws + 100 * MB);            // 512 KB
  int* cand            = (int*)(ws + 101 * MB);            // 1 MB
  int* cnt             = (int*)(ws + 102 * MB);            // 16 KB

  prep_kernel<<<18456, 256, 0, stream>>>(x, lng, lnb, xnh, xnm, xnl,
                                         rw2, w2b, pats, patsb, dirs, dirsb,
                                         opw, opwb, w1, w1b, rw1, w1h, w1m, w1l,
                                         nv, ipw, ipb, qtab);
  gemm1s<<<dim3(DM / 64, N_TOK / 64), 256, 0, stream>>>(xnh, xnm, xnl, w1h, w1m, w1l, h, hb);
  gemm_bf<<<dim3(DFF / 128, N_TOK / 128), 256, 0, stream>>>(hb, w2b, sb);
  topk2_kernel<<<N_TOK / 4, 256, 0, stream>>>(sb, cand, cnt);
  rescore_kernel<<<N_TOK, 256, 0, stream>>>(h, rw2, cand, cnt, idx32);
  tail9_kernel<<<N_TOK / 2, 512, 0, stream>>>(x, patsb, dirsb, qtab, idx32,
                                              opwb, opb, w1b, b1, w2, b2, out);
}

// Round 16
// 453.498 us; speedup vs baseline: 1.0557x; 1.0557x over previous
//
#include <hip/hip_runtime.h>
#include <math.h>

#define N_TOK 4096
#define DM 1024
#define DFF 4096
#define DN 128
#define NH 8
#define HD 16
#define KSEL 32
#define KCAND 48
#define KMAX 64

typedef __attribute__((ext_vector_type(4))) float floatx4;
typedef __attribute__((ext_vector_type(8))) short short8;
typedef __attribute__((ext_vector_type(8))) unsigned short ushort8v;
typedef __attribute__((ext_vector_type(4))) unsigned short ushort4v;

__device__ __forceinline__ float gelu_f(float x) {
  return 0.5f * x * (1.0f + erff(x * 0.70710678118654752440f));
}
__device__ __forceinline__ float bf2f(unsigned short u) {
  union { unsigned int i; float f; } v; v.i = ((unsigned int)u) << 16; return v.f;
}
__device__ __forceinline__ unsigned short f2bf(float f) {
  unsigned int x = __float_as_uint(f);
  unsigned int r = (x + 0x7fffu + ((x >> 16) & 1u)) >> 16;
  return (unsigned short)r;
}
// triple-bf16 split: v = hi + mid + lo to ~24 significant bits
__device__ __forceinline__ void split3(float v, unsigned short& h, unsigned short& m,
                                       unsigned short& lo) {
  h = f2bf(v);
  float r1 = v - bf2f(h);
  m = f2bf(r1);
  float r2 = r1 - bf2f(m);
  lo = f2bf(r2);
}

// ---------------- prep + LayerNorm merged: ONE launch (no qkvtab - register budget) ----------------
// blocks [0,4096): ln3 per-token | [4096,8192): rw2->w2b | [8192,12288): pats->patsb
// [12288,16384): dirs->dirsb | [16384,16400): opw->opwb | [16400,16408): w1->w1b
// [16408,17432): rw1->split3
__global__ __launch_bounds__(256) void prep_kernel(
    const float* __restrict__ x, const float* __restrict__ g, const float* __restrict__ bb_,
    unsigned short* __restrict__ xh, unsigned short* __restrict__ xm,
    unsigned short* __restrict__ xl,
    const float* __restrict__ rw2, unsigned short* __restrict__ w2b,
    const float* __restrict__ pats, unsigned short* __restrict__ patsb,
    const float* __restrict__ dirs, unsigned short* __restrict__ dirsb,
    const float* __restrict__ opw, unsigned short* __restrict__ opwb,
    const float* __restrict__ w1, unsigned short* __restrict__ w1b,
    const float* __restrict__ rw1, unsigned short* __restrict__ w1h,
    unsigned short* __restrict__ w1m, unsigned short* __restrict__ w1l) {
  int b = blockIdx.x, t = threadIdx.x;
  if (b < 4096) {
    // LayerNorm -> split bf16 triple for token b
    int n = b;
    const float* row = x + (size_t)n * DM;
    float s = 0.f, sq = 0.f;
    for (int i = t; i < DM; i += 256) { float v = row[i]; s += v; sq += v * v; }
    for (int off = 32; off; off >>= 1) { s += __shfl_down(s, off); sq += __shfl_down(sq, off); }
    __shared__ float ss[4], ssq[4];
    __shared__ float s_mu, s_rs;
    int wid = t >> 6;
    if ((t & 63) == 0) { ss[wid] = s; ssq[wid] = sq; }
    __syncthreads();
    if (t == 0) {
      float S = ss[0] + ss[1] + ss[2] + ss[3];
      float Q = ssq[0] + ssq[1] + ssq[2] + ssq[3];
      float mu = S * (1.f / DM);
      float var = Q * (1.f / DM) - mu * mu;
      s_mu = mu; s_rs = rsqrtf(var + 1e-5f);
    }
    __syncthreads();
    float mu = s_mu, rs = s_rs;
    size_t base = (size_t)n * DM;
    for (int i = t; i < DM; i += 256) {
      float v = (row[i] - mu) * rs * g[i] + bb_[i];
      unsigned short h, m, lo;
      split3(v, h, m, lo);
      xh[base + i] = h; xm[base + i] = m; xl[base + i] = lo;
    }
    return;
  }
  int bp = b - 4096;
  if (bp < 12288) {
    const float* src; unsigned short* dst; int local;
    if (bp < 4096) { src = rw2; dst = w2b; local = bp; }
    else if (bp < 8192) { src = pats; dst = patsb; local = bp - 4096; }
    else { src = dirs; dst = dirsb; local = bp - 8192; }
    int i = (local * 256 + t) * 4;
    float4 v = *(const float4*)(src + i);
    ushort4v o = {f2bf(v.x), f2bf(v.y), f2bf(v.z), f2bf(v.w)};
    *(ushort4v*)(dst + i) = o;
  } else if (bp < 12304) {
    int i = ((bp - 12288) * 256 + t) * 4;
    float4 v = *(const float4*)(opw + i);
    ushort4v o = {f2bf(v.x), f2bf(v.y), f2bf(v.z), f2bf(v.w)};
    *(ushort4v*)(opwb + i) = o;
  } else if (bp < 12312) {
    int i = ((bp - 12304) * 256 + t) * 4;
    float4 v = *(const float4*)(w1 + i);
    ushort4v o = {f2bf(v.x), f2bf(v.y), f2bf(v.z), f2bf(v.w)};
    *(ushort4v*)(w1b + i) = o;
  } else {
    int i = ((bp - 12312) * 256 + t) * 4;
    float4 v = *(const float4*)(rw1 + i);
    unsigned short h0, m0, l0, h1, m1, l1, h2, m2, l2, h3, m3, l3;
    split3(v.x, h0, m0, l0);
    split3(v.y, h1, m1, l1);
    split3(v.z, h2, m2, l2);
    split3(v.w, h3, m3, l3);
    ushort4v hh = {h0, h1, h2, h3};
    ushort4v mm = {m0, m1, m2, m3};
    ushort4v ll = {l0, l1, l2, l3};
    *(ushort4v*)(w1h + i) = hh;
    *(ushort4v*)(w1m + i) = mm;
    *(ushort4v*)(w1l + i) = ll;
  }
}

// ------- per-neuron qkv table (bf16 out) -------
__global__ __launch_bounds__(384) void qkvtab_kernel(const float* __restrict__ nv,
    const float* __restrict__ ipw, const float* __restrict__ ipb,
    unsigned short* __restrict__ tab) {
  __shared__ float s_nv[8 * 128];
  int f0 = blockIdx.x * 8;
  int tid = threadIdx.x;
  for (int i = tid; i < 8 * 128; i += 384) s_nv[i] = nv[(size_t)f0 * 128 + i];
  __syncthreads();
  int row = tid;
  float bias = ipb[row];
  float acc[8];
#pragma unroll
  for (int ff = 0; ff < 8; ff++) acc[ff] = bias;
  const float* wr = ipw + (size_t)row * 128;
  for (int c = 0; c < 128; c++) {
    float w = wr[c];
#pragma unroll
    for (int ff = 0; ff < 8; ff++) acc[ff] = fmaf(s_nv[ff * 128 + c], w, acc[ff]);
  }
#pragma unroll
  for (int ff = 0; ff < 8; ff++) tab[(size_t)(f0 + ff) * 384 + row] = f2bf(acc[ff]);
}

// ---------------- gemm1: h = gelu(xn @ W1^T) via triple-bf16 MFMA ----------------
// 64x64 tile, 1024 blocks (4/CU, 16 waves/CU). Wave layout 2x2, acc[2][2].
__global__ __launch_bounds__(256) void gemm1s(
    const unsigned short* __restrict__ Ah_, const unsigned short* __restrict__ Am_,
    const unsigned short* __restrict__ Al_, const unsigned short* __restrict__ Bh_,
    const unsigned short* __restrict__ Bm_, const unsigned short* __restrict__ Bl_,
    float* __restrict__ H, unsigned short* __restrict__ Hb) {
  __shared__ short Ahs[64 * 32], Ams[64 * 32], Als[64 * 32];
  __shared__ short Bhs[64 * 32], Bms[64 * 32], Bls[64 * 32];
  const int K = 1024;
  const int N = DM;
  int tid = threadIdx.x;
  int w = tid >> 6, l = tid & 63;
  int wr = w >> 1, wc = w & 1;
  size_t brow = (size_t)blockIdx.y * 64;
  size_t bcol = (size_t)blockIdx.x * 64;

  int r0 = w * 16 + (l >> 2);
  int g0 = (l & 3) ^ ((r0 >> 1) & 3);
  size_t oA = (brow + r0) * (size_t)K + g0 * 8;
  size_t oB = (bcol + r0) * (size_t)K + g0 * 8;
  const short* gAh = (const short*)Ah_ + oA;
  const short* gAm = (const short*)Am_ + oA;
  const short* gAl = (const short*)Al_ + oA;
  const short* gBh = (const short*)Bh_ + oB;
  const short* gBm = (const short*)Bm_ + oB;
  const short* gBl = (const short*)Bl_ + oB;
  short* lAh = &Ahs[w * 512]; short* lAm = &Ams[w * 512]; short* lAl = &Als[w * 512];
  short* lBh = &Bhs[w * 512]; short* lBm = &Bms[w * 512]; short* lBl = &Bls[w * 512];

  const short8 *pah[2], *pam[2], *pal[2], *pbh[2], *pbm[2], *pbl[2];
#pragma unroll
  for (int i = 0; i < 2; i++) {
    int m = wr * 32 + i * 16 + (l & 15);
    int slot = m * 4 + ((l >> 4) ^ ((m >> 1) & 3));
    pah[i] = (const short8*)&Ahs[slot * 8];
    pam[i] = (const short8*)&Ams[slot * 8];
    pal[i] = (const short8*)&Als[slot * 8];
    int nn = wc * 32 + i * 16 + (l & 15);
    int slotb = nn * 4 + ((l >> 4) ^ ((nn >> 1) & 3));
    pbh[i] = (const short8*)&Bhs[slotb * 8];
    pbm[i] = (const short8*)&Bms[slotb * 8];
    pbl[i] = (const short8*)&Bls[slotb * 8];
  }

  floatx4 acc[2][2];
#pragma unroll
  for (int i = 0; i < 2; i++)
#pragma unroll
    for (int j = 0; j < 2; j++) acc[i][j] = (floatx4){0.f, 0.f, 0.f, 0.f};

#define GLD(GP, LB) \
  __builtin_amdgcn_global_load_lds((const __attribute__((address_space(1))) unsigned int*)(GP), \
                                   (__attribute__((address_space(3))) unsigned int*)(LB), 16, 0, 0)

  for (int k0 = 0; k0 < K; k0 += 32) {
    __syncthreads();
    GLD(gAh + k0, lAh); GLD(gAm + k0, lAm); GLD(gAl + k0, lAl);
    GLD(gBh + k0, lBh); GLD(gBm + k0, lBm); GLD(gBl + k0, lBl);
    __syncthreads();
    short8 ah[2], am[2], al[2], bh[2], bm[2], bl[2];
#pragma unroll
    for (int i = 0; i < 2; i++) {
      ah[i] = *pah[i]; am[i] = *pam[i]; al[i] = *pal[i];
      bh[i] = *pbh[i]; bm[i] = *pbm[i]; bl[i] = *pbl[i];
    }
    // 6 split-product passes (hh, mh, hm, lh, hl, mm)
#pragma unroll
    for (int i = 0; i < 2; i++)
#pragma unroll
      for (int j = 0; j < 2; j++)
        acc[i][j] = __builtin_amdgcn_mfma_f32_16x16x32_bf16(ah[i], bh[j], acc[i][j], 0, 0, 0);
#pragma unroll
    for (int i = 0; i < 2; i++)
#pragma unroll
      for (int j = 0; j < 2; j++)
        acc[i][j] = __builtin_amdgcn_mfma_f32_16x16x32_bf16(am[i], bh[j], acc[i][j], 0, 0, 0);
#pragma unroll
    for (int i = 0; i < 2; i++)
#pragma unroll
      for (int j = 0; j < 2; j++)
        acc[i][j] = __builtin_amdgcn_mfma_f32_16x16x32_bf16(ah[i], bm[j], acc[i][j], 0, 0, 0);
#pragma unroll
    for (int i = 0; i < 2; i++)
#pragma unroll
      for (int j = 0; j < 2; j++)
        acc[i][j] = __builtin_amdgcn_mfma_f32_16x16x32_bf16(al[i], bh[j], acc[i][j], 0, 0, 0);
#pragma unroll
    for (int i = 0; i < 2; i++)
#pragma unroll
      for (int j = 0; j < 2; j++)
        acc[i][j] = __builtin_amdgcn_mfma_f32_16x16x32_bf16(ah[i], bl[j], acc[i][j], 0, 0, 0);
#pragma unroll
    for (int i = 0; i < 2; i++)
#pragma unroll
      for (int j = 0; j < 2; j++)
        acc[i][j] = __builtin_amdgcn_mfma_f32_16x16x32_bf16(am[i], bm[j], acc[i][j], 0, 0, 0);
  }
#undef GLD

#pragma unroll
  for (int i = 0; i < 2; i++) {
#pragma unroll
    for (int j = 0; j < 2; j++) {
#pragma unroll
      for (int r = 0; r < 4; r++) {
        size_t row = brow + wr * 32 + i * 16 + (l >> 4) * 4 + r;
        size_t col = bcol + wc * 32 + j * 16 + (l & 15);
        float v = gelu_f(acc[i][j][r]);
        H[row * N + col] = v;
        Hb[row * N + col] = f2bf(v);
      }
    }
  }
}

// ---------------- bf16 MFMA GEMM: scores_approx(bf16) = hb @ w2b^T ----------------
__global__ __launch_bounds__(256) void gemm_bf(const unsigned short* __restrict__ Ah,
    const unsigned short* __restrict__ Bh, unsigned short* __restrict__ C) {
  __shared__ short Asd[128 * 32];
  __shared__ short Bsd[128 * 32];
  const int K = 1024;
  int tid = threadIdx.x;
  int w = tid >> 6, l = tid & 63;
  size_t brow = (size_t)blockIdx.y * 128;
  size_t bcol = (size_t)blockIdx.x * 128;
  const short* Ab = (const short*)Ah + brow * K;
  const short* Bb = (const short*)Bh + bcol * K;

  int r0 = w * 32 + (l >> 2);
  int g0 = (l & 3) ^ ((r0 >> 1) & 3);
  const short* Ag0 = Ab + (size_t)r0 * K + g0 * 8;
  const short* Ag1 = Ab + (size_t)(r0 + 16) * K + g0 * 8;
  const short* Bg0 = Bb + (size_t)r0 * K + g0 * 8;
  const short* Bg1 = Bb + (size_t)(r0 + 16) * K + g0 * 8;
  short* ALds0 = &Asd[w * 1024];
  short* ALds1 = &Asd[w * 1024 + 512];
  short* BLds0 = &Bsd[w * 1024];
  short* BLds1 = &Bsd[w * 1024 + 512];

  const short8* aptr[4];
  const short8* bptr[4];
#pragma unroll
  for (int i = 0; i < 4; i++) {
    int m = (w >> 1) * 64 + i * 16 + (l & 15);
    int slot = m * 4 + ((l >> 4) ^ ((m >> 1) & 3));
    aptr[i] = (const short8*)&Asd[slot * 8];
    int n = (w & 1) * 64 + i * 16 + (l & 15);
    int slotb = n * 4 + ((l >> 4) ^ ((n >> 1) & 3));
    bptr[i] = (const short8*)&Bsd[slotb * 8];
  }

  floatx4 acc[4][4];
#pragma unroll
  for (int i = 0; i < 4; i++)
#pragma unroll
    for (int j = 0; j < 4; j++) acc[i][j] = (floatx4){0.f, 0.f, 0.f, 0.f};

  for (int k0 = 0; k0 < K; k0 += 32) {
    __syncthreads();
    __builtin_amdgcn_global_load_lds((const __attribute__((address_space(1))) unsigned int*)(Ag0 + k0),
                                     (__attribute__((address_space(3))) unsigned int*)ALds0, 16, 0, 0);
    __builtin_amdgcn_global_load_lds((const __attribute__((address_space(1))) unsigned int*)(Ag1 + k0),
                                     (__attribute__((address_space(3))) unsigned int*)ALds1, 16, 0, 0);
    __builtin_amdgcn_global_load_lds((const __attribute__((address_space(1))) unsigned int*)(Bg0 + k0),
                                     (__attribute__((address_space(3))) unsigned int*)BLds0, 16, 0, 0);
    __builtin_amdgcn_global_load_lds((const __attribute__((address_space(1))) unsigned int*)(Bg1 + k0),
                                     (__attribute__((address_space(3))) unsigned int*)BLds1, 16, 0, 0);
    __syncthreads();
    short8 a[4], b[4];
#pragma unroll
    for (int i = 0; i < 4; i++) a[i] = *aptr[i];
#pragma unroll
    for (int j = 0; j < 4; j++) b[j] = *bptr[j];
#pragma unroll
    for (int i = 0; i < 4; i++)
#pragma unroll
      for (int j = 0; j < 4; j++)
        acc[i][j] = __builtin_amdgcn_mfma_f32_16x16x32_bf16(a[i], b[j], acc[i][j], 0, 0, 0);
  }

#pragma unroll
  for (int i = 0; i < 4; i++) {
#pragma unroll
    for (int j = 0; j < 4; j++) {
#pragma unroll
      for (int r = 0; r < 4; r++) {
        size_t row = brow + (w >> 1) * 64 + i * 16 + (l >> 4) * 4 + r;
        size_t col = bcol + (w & 1) * 64 + j * 16 + (l & 15);
        C[row * DFF + col] = f2bf(acc[i][j][r]);
      }
    }
  }
}

// ---------------- top-candidates per row: wave-per-token radix select ----------------
__global__ __launch_bounds__(256) void topk2_kernel(const unsigned short* __restrict__ scores,
    int* __restrict__ cand, int* __restrict__ cnt) {
  int wv = threadIdx.x >> 6, l = threadIdx.x & 63;
  int n = blockIdx.x * 4 + wv;
  const ushort8v* row = (const ushort8v*)(scores + (size_t)n * DFF);
  unsigned short key[64];
#pragma unroll
  for (int i = 0; i < 8; i++) {
    ushort8v v = row[l * 8 + i];
#pragma unroll
    for (int e = 0; e < 8; e++) {
      unsigned short u = v[e];
      key[i * 8 + e] = (u & 0x8000u) ? (unsigned short)(~u)
                                     : (unsigned short)(u | 0x8000u);
    }
  }
  unsigned int prefix = 0;
#pragma unroll
  for (int bit = 15; bit >= 0; bit--) {
    unsigned int probe = prefix | (1u << bit);
    int c = 0;
#pragma unroll
    for (int i = 0; i < 64; i++) c += (key[i] >= probe) ? 1 : 0;
#pragma unroll
    for (int s = 1; s < 64; s <<= 1) c += __shfl_xor(c, s);
    if (c >= KCAND) prefix = probe;
  }
  unsigned short thr = (unsigned short)prefix;
  unsigned long long ltmask = (1ull << l) - 1ull;
  int base = 0;
  int* outp = cand + (size_t)n * KMAX;
#pragma unroll
  for (int i = 0; i < 64; i++) {
    bool p = key[i] >= thr;
    unsigned long long m = __ballot(p);
    if (p) {
      int pos = base + __popcll(m & ltmask);
      if (pos < KMAX) outp[pos] = l * 64 + i;
    }
    base += __popcll(m);
  }
  if (l == 0) cnt[n] = base < KMAX ? base : KMAX;
}

// ---------------- fp32 rescore of candidates -> exact top-32 set ----------------
__global__ __launch_bounds__(256) void rescore_kernel(const float* __restrict__ h,
    const float* __restrict__ w2f, const int* __restrict__ cand,
    const int* __restrict__ cnt, int* __restrict__ idx32) {
  __shared__ float sh[DM];
  __shared__ float sc[KMAX];
  __shared__ int sidx[KMAX];
  __shared__ int s_cnt;
  int n = blockIdx.x, tid = threadIdx.x;
  *(float4*)&sh[tid * 4] = *(const float4*)(h + (size_t)n * DM + tid * 4);
  if (tid == 0) s_cnt = cnt[n];
  if (tid < KMAX) { sidx[tid] = cand[(size_t)n * KMAX + tid]; sc[tid] = -INFINITY; }
  __syncthreads();
  int cntv = s_cnt;
  int w = tid >> 6, lane = tid & 63;
  for (int c = w; c < cntv; c += 4) {
    const float4* row = (const float4*)(w2f + (size_t)sidx[c] * DM);
    const float4* hp = (const float4*)sh;
    float s = 0.f;
#pragma unroll
    for (int t = 0; t < 4; t++) {
      float4 wv = row[t * 64 + lane];
      float4 hv = hp[t * 64 + lane];
      s = fmaf(wv.x, hv.x, s); s = fmaf(wv.y, hv.y, s);
      s = fmaf(wv.z, hv.z, s); s = fmaf(wv.w, hv.w, s);
    }
    for (int off = 32; off; off >>= 1) s += __shfl_xor(s, off);
    if (lane == 0) sc[c] = s;
  }
  __syncthreads();
  if (tid < cntv) {
    float st = sc[tid]; int it = sidx[tid];
    int rank = 0;
    for (int j = 0; j < KMAX; j++) {
      float sj = sc[j];
      rank += (sj > st) || (sj == st && sidx[j] < it);
    }
    if (rank < KSEL) idx32[(size_t)n * KSEL + rank] = it;
  }
}

// ---------------- tail v9b: 2 tokens/block (512 thr); MFMA attention per 4-wave half ----------------
#define KS 132
#define AOS 132
__global__ __launch_bounds__(512) void tail9_kernel(
    const float* __restrict__ xf, const unsigned short* __restrict__ pats_b,
    const unsigned short* __restrict__ dirs_b, const unsigned short* __restrict__ qtab_b,
    const int* __restrict__ idxs,
    const unsigned short* __restrict__ opwb, const float* __restrict__ opb,
    const unsigned short* __restrict__ w1b, const float* __restrict__ b1,
    const float* __restrict__ w2, const float* __restrict__ b2,
    float* __restrict__ out) {
  __shared__ unsigned short s_q[2][32 * KS];
  __shared__ unsigned short s_k[2][32 * KS];
  __shared__ unsigned short s_v[2][32 * KS];
  __shared__ float s_base[2][32];
  __shared__ float s_coef[2][32];
  __shared__ int s_idx[2][32];

  int tid512 = threadIdx.x;
  int tk = tid512 >> 8;                       // token half 0/1
  int tid = tid512 & 255;                     // 0..255 within half
  int n = blockIdx.x * 2 + tk;
  int w = tid >> 6, l = tid & 63;
  int g = l >> 4, lc = l & 15;
  unsigned short* s_ao = s_k[tk];             // aliases within this token's buffers
  unsigned short* s_at = s_v[tk];

  if (tid < 32) s_idx[tk][tid] = idxs[(size_t)n * 32 + tid];
  __syncthreads();   // s_idx ready (both tokens)

  // stage Q, K, V row-major (conflict-free 16B stores)
#pragma unroll
  for (int p = 0; p < 2; p++) {
    int i = p * 256 + tid;
    int j = i >> 4, cc = i & 15;
    const unsigned short* src = qtab_b + (size_t)s_idx[tk][j] * 384 + cc * 8;
    ushort8v qv = *(const ushort8v*)(src);
    ushort8v kv = *(const ushort8v*)(src + 128);
    ushort8v vv = *(const ushort8v*)(src + 256);
    *(ushort8v*)&s_q[tk][j * KS + cc * 8] = qv;
    *(ushort8v*)&s_k[tk][j * KS + cc * 8] = kv;
    *(ushort8v*)&s_v[tk][j * KS + cc * 8] = vv;
  }

  // base[j] = gelu(x . pats[idx[j]]) : 32 groups x 8 lanes; x from global (L1)
  {
    int j = tid >> 3, gq = tid & 7;
    const ushort8v* pr = (const ushort8v*)(pats_b + (size_t)s_idx[tk][j] * DM);
    const float4* xr = (const float4*)(xf + (size_t)n * DM);
    float s = 0.f;
#pragma unroll 4
    for (int it = 0; it < 16; it++) {
      int ch = it * 8 + gq;
      ushort8v pv = pr[ch];
      float4 xv0 = xr[ch * 2];
      float4 xv1 = xr[ch * 2 + 1];
      s = fmaf(bf2f(pv[0]), xv0.x, s); s = fmaf(bf2f(pv[1]), xv0.y, s);
      s = fmaf(bf2f(pv[2]), xv0.z, s); s = fmaf(bf2f(pv[3]), xv0.w, s);
      s = fmaf(bf2f(pv[4]), xv1.x, s); s = fmaf(bf2f(pv[5]), xv1.y, s);
      s = fmaf(bf2f(pv[6]), xv1.z, s); s = fmaf(bf2f(pv[7]), xv1.w, s);
    }
    s += __shfl_xor(s, 1);
    s += __shfl_xor(s, 2);
    s += __shfl_xor(s, 4);
    if (gq == 0) s_base[tk][j] = gelu_f(s);
  }
  __syncthreads();   // Q/K/V staged

  // ---- QK (swapped, MFMA) + softmax + P^T repack ----
  short8 pB[2][2];
  {
    short8 zero8 = {0, 0, 0, 0, 0, 0, 0, 0};
    int srcA = (((2 * g) & 3) << 4) | lc;
    int srcB = (((2 * g + 1) & 3) << 4) | lc;
    bool hiSel = (g >= 2);
#pragma unroll
    for (int hh = 0; hh < 2; hh++) {
      int h = w * 2 + hh;
      short8 qf[2], kf[2];
#pragma unroll
      for (int qt = 0; qt < 2; qt++) {
        short8 q = zero8;
        if (g < 2) q = *(const short8*)&s_q[tk][(qt * 16 + lc) * KS + h * 16 + g * 8];
        qf[qt] = q;
      }
#pragma unroll
      for (int kt = 0; kt < 2; kt++) {
        short8 k = zero8;
        if (g < 2) k = *(const short8*)&s_k[tk][(kt * 16 + lc) * KS + h * 16 + g * 8];
        kf[kt] = k;
      }
      floatx4 c[2][2];
#pragma unroll
      for (int kt = 0; kt < 2; kt++)
#pragma unroll
        for (int qt = 0; qt < 2; qt++)
          c[kt][qt] = __builtin_amdgcn_mfma_f32_16x16x32_bf16(kf[kt], qf[qt],
                                                              (floatx4){0.f, 0.f, 0.f, 0.f}, 0, 0, 0);
#pragma unroll
      for (int qt = 0; qt < 2; qt++) {
        float v0[4], v1[4];
#pragma unroll
        for (int r = 0; r < 4; r++) { v0[r] = c[0][qt][r] * 0.25f; v1[r] = c[1][qt][r] * 0.25f; }
        float m = v0[0];
#pragma unroll
        for (int r = 1; r < 4; r++) m = fmaxf(m, v0[r]);
#pragma unroll
        for (int r = 0; r < 4; r++) m = fmaxf(m, v1[r]);
        m = fmaxf(m, __shfl_xor(m, 16));
        m = fmaxf(m, __shfl_xor(m, 32));
        float sum = 0.f;
#pragma unroll
        for (int r = 0; r < 4; r++) { v0[r] = expf(v0[r] - m); sum += v0[r]; }
#pragma unroll
        for (int r = 0; r < 4; r++) { v1[r] = expf(v1[r] - m); sum += v1[r]; }
        sum += __shfl_xor(sum, 16);
        sum += __shfl_xor(sum, 32);
        float inv = 1.f / sum;
        unsigned int u00 = ((unsigned int)f2bf(v0[1] * inv) << 16) | f2bf(v0[0] * inv);
        unsigned int u01 = ((unsigned int)f2bf(v0[3] * inv) << 16) | f2bf(v0[2] * inv);
        unsigned int u10 = ((unsigned int)f2bf(v1[1] * inv) << 16) | f2bf(v1[0] * inv);
        unsigned int u11 = ((unsigned int)f2bf(v1[3] * inv) << 16) | f2bf(v1[2] * inv);
        unsigned int a00 = (unsigned int)__shfl((int)u00, srcA);
        unsigned int a01 = (unsigned int)__shfl((int)u01, srcA);
        unsigned int a10 = (unsigned int)__shfl((int)u10, srcA);
        unsigned int a11 = (unsigned int)__shfl((int)u11, srcA);
        unsigned int b00 = (unsigned int)__shfl((int)u00, srcB);
        unsigned int b01 = (unsigned int)__shfl((int)u01, srcB);
        unsigned int b10 = (unsigned int)__shfl((int)u10, srcB);
        unsigned int b11 = (unsigned int)__shfl((int)u11, srcB);
        union { unsigned int u[4]; short8 s; } pb;
        pb.u[0] = hiSel ? a10 : a00;
        pb.u[1] = hiSel ? a11 : a01;
        pb.u[2] = hiSel ? b10 : b00;
        pb.u[3] = hiSel ? b11 : b01;
        pB[hh][qt] = pb.s;
      }
    }
  }
  __syncthreads();   // QK reads done -> s_ao may overwrite

  // ---- PV (MFMA): V^T frag from row-major s_v ----
  {
#pragma unroll
    for (int hh = 0; hh < 2; hh++) {
      int h = w * 2 + hh;
      short8 vtf;
#pragma unroll
      for (int e = 0; e < 8; e++)
        vtf[e] = (short)s_v[tk][(g * 8 + e) * KS + h * 16 + lc];
#pragma unroll
      for (int qt = 0; qt < 2; qt++) {
        floatx4 o = __builtin_amdgcn_mfma_f32_16x16x32_bf16(vtf, pB[hh][qt],
                                                            (floatx4){0.f, 0.f, 0.f, 0.f}, 0, 0, 0);
        ushort4v ov = {f2bf(o[0]), f2bf(o[1]), f2bf(o[2]), f2bf(o[3])};
        *(ushort4v*)&s_ao[(qt * 16 + lc) * AOS + h * 16 + g * 4] = ov;
      }
    }
  }
  __syncthreads();   // PV reads done; s_ao complete -> s_at may overwrite s_v

  // out_proj MFMA: 4-wave split per token: rows (w&1)*16, col-block (w>>1)*64
  {
    floatx4 acc[4];
#pragma unroll
    for (int nt = 0; nt < 4; nt++) acc[nt] = (floatx4){0.f, 0.f, 0.f, 0.f};
    int rbase = (w & 1) * 16;
    int cblk = (w >> 1) * 4;
#pragma unroll
    for (int kst = 0; kst < 4; kst++) {
      short8 a = *(const short8*)&s_ao[(rbase + lc) * AOS + kst * 32 + g * 8];
#pragma unroll
      for (int nt = 0; nt < 4; nt++) {
        short8 b = *(const short8*)&opwb[(size_t)((cblk + nt) * 16 + lc) * 128 + kst * 32 + g * 8];
        acc[nt] = __builtin_amdgcn_mfma_f32_16x16x32_bf16(a, b, acc[nt], 0, 0, 0);
      }
    }
#pragma unroll
    for (int nt = 0; nt < 4; nt++) {
      int col = (cblk + nt) * 16 + lc;
      float bias = opb[col];
#pragma unroll
      for (int r = 0; r < 4; r++) {
        int row = rbase + g * 4 + r;
        s_at[row * AOS + col] = f2bf(acc[nt][r] + bias);
      }
    }
  }
  __syncthreads();

  // gate MFMA: waves 0-1 of each token half: rows w*16, all 64 cols
  if (w < 2) {
    floatx4 acc[4];
#pragma unroll
    for (int nt = 0; nt < 4; nt++) acc[nt] = (floatx4){0.f, 0.f, 0.f, 0.f};
#pragma unroll
    for (int kst = 0; kst < 4; kst++) {
      short8 a = *(const short8*)&s_at[(w * 16 + lc) * AOS + kst * 32 + g * 8];
#pragma unroll
      for (int nt = 0; nt < 4; nt++) {
        short8 b = *(const short8*)&w1b[(size_t)(nt * 16 + lc) * 128 + kst * 32 + g * 8];
        acc[nt] = __builtin_amdgcn_mfma_f32_16x16x32_bf16(a, b, acc[nt], 0, 0, 0);
      }
    }
    float p[4] = {0.f, 0.f, 0.f, 0.f};
#pragma unroll
    for (int nt = 0; nt < 4; nt++) {
      int col = nt * 16 + lc;
      float bb = b1[col], ww = w2[col];
#pragma unroll
      for (int r = 0; r < 4; r++)
        p[r] = fmaf(gelu_f(acc[nt][r] + bb), ww, p[r]);
    }
#pragma unroll
    for (int r = 0; r < 4; r++) {
      p[r] += __shfl_xor(p[r], 1);
      p[r] += __shfl_xor(p[r], 2);
      p[r] += __shfl_xor(p[r], 4);
      p[r] += __shfl_xor(p[r], 8);
    }
    if (lc == 0) {
      float b2v = b2[0];
#pragma unroll
      for (int r = 0; r < 4; r++) {
        int row = w * 16 + g * 4 + r;
        float sw = 1.f / (1.f + expf(-(p[r] + b2v)));
        s_coef[tk][row] = s_base[tk][row] * sw;
      }
    }
  }
  __syncthreads();

  // output: out[n][d] = sum_j coef[j] * dirs_b[idx[j]][d] (bf16 dirs)
  {
    int d0 = tid * 4;
    float4 a = {0.f, 0.f, 0.f, 0.f};
#pragma unroll 8
    for (int j = 0; j < 32; j++) {
      float c = s_coef[tk][j];
      ushort4v dv = *(const ushort4v*)&dirs_b[(size_t)s_idx[tk][j] * DM + d0];
      a.x = fmaf(c, bf2f(dv.x), a.x);
      a.y = fmaf(c, bf2f(dv.y), a.y);
      a.z = fmaf(c, bf2f(dv.z), a.z);
      a.w = fmaf(c, bf2f(dv.w), a.w);
    }
    *(float4*)&out[(size_t)n * 1024 + d0] = a;
  }
}

extern "C" void kernel_launch(void* const* d_in, const int* in_sizes, int n_in,
                              void* d_out, int out_size, void* d_ws, size_t ws_size,
                              hipStream_t stream) {
  const float* x    = (const float*)d_in[0];
  const float* pats = (const float*)d_in[1];
  const float* nv   = (const float*)d_in[2];
  const float* dirs = (const float*)d_in[3];
  const float* rw1  = (const float*)d_in[4];
  const float* rw2  = (const float*)d_in[5];
  const float* lng  = (const float*)d_in[6];
  const float* lnb  = (const float*)d_in[7];
  const float* ipw  = (const float*)d_in[8];
  const float* ipb  = (const float*)d_in[9];
  const float* opw  = (const float*)d_in[10];
  const float* opb  = (const float*)d_in[11];
  const float* w1   = (const float*)d_in[12];
  const float* b1   = (const float*)d_in[13];
  const float* w2   = (const float*)d_in[14];
  const float* b2   = (const float*)d_in[15];
  float* out = (float*)d_out;

  const size_t MB = 1u << 20;
  char* ws = (char*)d_ws;
  unsigned short* xnh  = (unsigned short*)(ws + 0);        // 8 MB (split xn hi)
  unsigned short* xnm  = (unsigned short*)(ws + 8 * MB);   // 8 MB (split xn mid)
  float* h             = (float*)(ws + 16 * MB);           // 16 MB
  unsigned short* sb   = (unsigned short*)(ws + 32 * MB);  // 32 MB (bf16 scores)
  // transient buffers inside sb region: consumed by gemm1s BEFORE gemm_bf writes sb
  unsigned short* w1h  = (unsigned short*)(ws + 32 * MB);  // 2 MB
  unsigned short* w1m  = (unsigned short*)(ws + 34 * MB);  // 2 MB
  unsigned short* w1l  = (unsigned short*)(ws + 36 * MB);  // 2 MB
  unsigned short* xnl  = (unsigned short*)(ws + 38 * MB);  // 8 MB (split xn lo)
  unsigned short* qtab = (unsigned short*)(ws + 64 * MB);  // 3 MB
  unsigned short* hb   = (unsigned short*)(ws + 67 * MB);  // 8 MB
  unsigned short* w2b  = (unsigned short*)(ws + 75 * MB);  // 8 MB
  unsigned short* patsb= (unsigned short*)(ws + 83 * MB);  // 8 MB
  unsigned short* dirsb= (unsigned short*)(ws + 91 * MB);  // 8 MB
  unsigned short* opwb = (unsigned short*)(ws + 99 * MB);  // 32 KB
  unsigned short* w1b  = (unsigned short*)(ws + 99 * MB + 64 * 1024);  // 16 KB
  int* idx32           = (int*)(ws + 100 * MB);            // 512 KB
  int* cand            = (int*)(ws + 101 * MB);            // 1 MB
  int* cnt             = (int*)(ws + 102 * MB);            // 16 KB

  prep_kernel<<<17432, 256, 0, stream>>>(x, lng, lnb, xnh, xnm, xnl,
                                         rw2, w2b, pats, patsb, dirs, dirsb,
                                         opw, opwb, w1, w1b, rw1, w1h, w1m, w1l);
  gemm1s<<<dim3(DM / 64, N_TOK / 64), 256, 0, stream>>>(xnh, xnm, xnl, w1h, w1m, w1l, h, hb);
  gemm_bf<<<dim3(DFF / 128, N_TOK / 128), 256, 0, stream>>>(hb, w2b, sb);
  topk2_kernel<<<N_TOK / 4, 256, 0, stream>>>(sb, cand, cnt);
  rescore_kernel<<<N_TOK, 256, 0, stream>>>(h, rw2, cand, cnt, idx32);
  qkvtab_kernel<<<DFF / 8, 384, 0, stream>>>(nv, ipw, ipb, qtab);
  tail9_kernel<<<N_TOK / 2, 512, 0, stream>>>(x, patsb, dirsb, qtab, idx32,
                                              opwb, opb, w1b, b1, w2, b2, out);
}